// Round 4
// baseline (545.015 us; speedup 1.0000x reference)
//
#include <hip/hip_runtime.h>

// Problem constants: B=2, N=4096, NS=32, H=8, HD=32, G=16
constexpr int NSC = 32;   // neighbors
constexpr int CC  = 256;  // H*HD channels
constexpr int GG  = 16;   // geo features

// Math (validated by round-3 passing bench):
//   score[h,d] = sum_s we[s,h,d]*Weff[s] + beff,  Weff[s]=sum_t W2[t]*W1[t,s]
//   weight'[s,h] = gw[s] - sum_d k[s,h,d]*score[h,d]   (q-term s-constant, dropped
//   under softmax shift-invariance); gw[s] = sum_g geo[s,g]*sgeo[g],
//   sgeo[g] = beff + sum_s' geo[s',g]*Weff[s'].
//
// Layout insight: head h spans channels [h*32, h*32+32) == one half-wave.
// Lane owns one channel column; all d-reductions are width-32 butterflies;
// all s-reductions are lane-local register FMAs. No LDS, no barriers.

__global__ void setup_weff(const float* __restrict__ W1, const float* __restrict__ b1,
                           const float* __restrict__ W2, const float* __restrict__ b2,
                           float* __restrict__ ws) {
    const int t = threadIdx.x;
    if (t < 32) {
        float acc = 0.f;
#pragma unroll
        for (int tt = 0; tt < 32; ++tt) acc += W2[tt] * W1[tt * 32 + t];
        ws[t] = acc;                       // Weff[s]
        float wsum = acc;
#pragma unroll
        for (int m = 16; m >= 1; m >>= 1) wsum += __shfl_xor(wsum, m, 32);
        if (t == 0) {
            float beff = b2[0];
#pragma unroll
            for (int tt = 0; tt < 32; ++tt) beff += W2[tt] * b1[tt];
            ws[32] = beff;
            ws[33] = wsum;                 // sum_s Weff[s]
        }
    }
}

__global__ __launch_bounds__(256, 4)
void geoneigh_att_kernel(const float* __restrict__ q,
                         const float* __restrict__ kng,
                         const float* __restrict__ vng,
                         const float* __restrict__ geo,
                         const float* __restrict__ ws,
                         float* __restrict__ out)
{
    const int t  = threadIdx.x;
    const int bn = blockIdx.x;
    const int c  = t;            // channel (h = c>>5)
    const int sl = t & 31;       // this lane's s-slot within its half-wave

    const size_t kvbase = (size_t)bn * (NSC * CC);
    const float* kp = kng + kvbase;
    const float* vp = vng + kvbase;
    const float* gp = geo + (size_t)bn * (NSC * GG);

    // k column for channel c: 32 coalesced dword loads (256B/wave-instr)
    float kreg[NSC];
#pragma unroll
    for (int s = 0; s < NSC; ++s) kreg[s] = kp[s * CC + c];

    // geo row for s = sl (L1/L2-hot broadcast; HBM reads it exactly once)
    float georeg[GG];
#pragma unroll
    for (int g = 0; g < GG; ++g) georeg[g] = gp[sl * GG + g];

    const float weffr = ws[sl];          // per-lane Weff[sl]
    const float beff  = ws[32];          // uniform -> scalar load
    const float wsum  = ws[33];
    const float qv = q[(size_t)bn * CC + c] * 0.17677669529663687f;  // HD^-0.5

    // ---- score[c] = qv*wsum - sum_s k[s,c]*Weff[s] + beff  (lane-local) ----
    float kd = 0.f;
#pragma unroll
    for (int s = 0; s < NSC; ++s) kd += kreg[s] * ws[s];   // ws[s]: scalar-load op
    const float score = qv * wsum - kd + beff;

    // ---- gw[sl] = sum_g geo[sl,g] * sgeo[g];  sgeo via half-wave butterfly ----
    float gw = 0.f;
#pragma unroll
    for (int g = 0; g < GG; ++g) {
        float p = georeg[g] * weffr;
#pragma unroll
        for (int m = 16; m >= 1; m >>= 1) p += __shfl_xor(p, m, 32);
        gw += georeg[g] * (p + beff);
    }

    // ---- weight'[s] = gw[s] - sum_d k[s,h,d]*score[h,d]; keep own s=sl ----
    float wsel = 0.f;
#pragma unroll
    for (int s = 0; s < NSC; ++s) {
        float p = kreg[s] * score;
#pragma unroll
        for (int m = 16; m >= 1; m >>= 1) p += __shfl_xor(p, m, 32);
        const float w_s = __shfl(gw, s, 32) - p;
        wsel = (sl == s) ? w_s : wsel;
    }

    // ---- softmax over s = over the 32 lanes of this half-wave ----
    float mx = wsel;
#pragma unroll
    for (int m = 16; m >= 1; m >>= 1) mx = fmaxf(mx, __shfl_xor(mx, m, 32));
    const float e = __expf(wsel - mx);
    float se = e;
#pragma unroll
    for (int m = 16; m >= 1; m >>= 1) se += __shfl_xor(se, m, 32);
    const float attn = e / se;           // attn[sl, h]

    // ---- out[c] = sum_s attn[s]*v[s,c]  (coalesced v column reads) ----
    float acc = 0.f;
#pragma unroll
    for (int s = 0; s < NSC; ++s) acc += __shfl(attn, s, 32) * vp[s * CC + c];
    out[(size_t)bn * CC + c] = acc;
}

extern "C" void kernel_launch(void* const* d_in, const int* in_sizes, int n_in,
                              void* d_out, int out_size, void* d_ws, size_t ws_size,
                              hipStream_t stream) {
    const float* q   = (const float*)d_in[0];
    const float* kng = (const float*)d_in[1];
    const float* vng = (const float*)d_in[2];
    const float* geo = (const float*)d_in[3];
    const float* W1  = (const float*)d_in[4];
    const float* b1  = (const float*)d_in[5];
    const float* W2  = (const float*)d_in[6];
    const float* b2  = (const float*)d_in[7];
    float* out = (float*)d_out;
    float* ws  = (float*)d_ws;   // 34 floats: Weff[32], beff, wsum

    setup_weff<<<1, 64, 0, stream>>>(W1, b1, W2, b2, ws);
    const int tokens = 2 * 4096;
    geoneigh_att_kernel<<<tokens, 256, 0, stream>>>(q, kng, vng, geo, ws, out);
}